// Round 9
// baseline (206.262 us; speedup 1.0000x reference)
//
#include <hip/hip_runtime.h>

// Native clang vector type — required by __builtin_nontemporal_{load,store}
// and supports elementwise +=.
typedef float f32x4 __attribute__((ext_vector_type(4)));

// Problem constants (from reference):
constexpr int kB  = 256;    // batch
constexpr int kN  = 1000;   // classes
constexpr int kA  = 32;     // attention parts
constexpr int kC  = 512;    // channels
constexpr int kAC = kA * kC;            // 16384 floats per (class or sample)
constexpr int kFeat  = kB * kAC;        // 4,194,304 floats
constexpr int kCache = kN * kAC;        // 16,384,000 floats
constexpr int kRows  = kB * kA;         // 8192 (b,a) rows of 512 floats

constexpr int kF4PerClass = kAC / 4;    // 4096 f32x4 per class/sample row
constexpr int kTileF4 = 2048;           // f32x4 per block tile (32 KB)
constexpr int kATiles = (kCache / 4) / kTileF4;  // 2000 (cache region)
constexpr int kBTiles = (kFeat  / 4) / kTileF4;  // 512  (exchange region)
constexpr int kTiles  = kATiles + kBTiles;       // 2512

// ws layout (bytes): masks[4000 u64] @0, cls[256 int] @32000,
//                    srcrow[8192 int] @33024
constexpr int kWsMasksOff  = 0;
constexpr int kWsClsOff    = 32000;
constexpr int kWsSrcrowOff = 33024;
constexpr int kWsCntOff    = 65792;

// ---------------------------------------------------------------------------
// Kernel 1: per-sample wave: cls[b] = argmax_n labels[b,n] (first-max), then
// lanes 0..31 compute the per-(b,a)-row source descriptor:
//   srcrow[row] = (rand_u[row] > 0.5) ? 0x80000000 | (cls*32 + a) : row
// ---------------------------------------------------------------------------
__global__ __launch_bounds__(256) void k_prep(
    const float* __restrict__ labels,
    const float* __restrict__ rand_u,
    int* __restrict__ cls,
    int* __restrict__ srcrow)
{
    const int wave = threadIdx.x >> 6;
    const int lane = threadIdx.x & 63;
    const int b = blockIdx.x * 4 + wave;
    const float* row = labels + (size_t)b * kN;
    float best = -3.4e38f;
    int   bidx = kN;
    for (int n = lane; n < kN; n += 64) {
        float v = row[n];                      // coalesced across lanes
        if (v > best) { best = v; bidx = n; }  // ascending n => first max kept
    }
    #pragma unroll
    for (int off = 32; off >= 1; off >>= 1) {  // butterfly: all lanes converge
        float ov = __shfl_xor(best, off, 64);
        int   oi = __shfl_xor(bidx, off, 64);
        if (ov > best || (ov == best && oi < bidx)) { best = ov; bidx = oi; }
    }
    if (lane == 0) cls[b] = bidx;
    if (lane < kA) {
        const int r = b * kA + lane;
        const float ru = rand_u[r];
        srcrow[r] = (ru > 0.5f) ? (int)(0x80000000u | (unsigned)(bidx * kA + lane))
                                : r;
    }
}

// ---------------------------------------------------------------------------
// Kernel 2 (tiny, 4 blocks): per-class match masks + counts, and new_count.
// Moves ALL ballot/barrier work out of the streaming kernel. Thread n scans
// the 256 cls entries from LDS (broadcast reads, lockstep across threads).
// ---------------------------------------------------------------------------
__global__ __launch_bounds__(256) void k_plan(
    const int*   __restrict__ cls,
    const float* __restrict__ count,
    unsigned long long* __restrict__ masks,
    int*   __restrict__ cnt,
    float* __restrict__ out_count)
{
    __shared__ int scls[kB];
    scls[threadIdx.x] = cls[threadIdx.x];
    __syncthreads();

    const int n = blockIdx.x * 256 + threadIdx.x;
    if (n >= kN) return;

    unsigned long long m[4] = {0, 0, 0, 0};
    #pragma unroll
    for (int w = 0; w < 4; ++w)
        for (int b = 0; b < 64; ++b)
            m[w] |= (unsigned long long)(scls[w * 64 + b] == n) << b;

    int tot = 0;
    #pragma unroll
    for (int w = 0; w < 4; ++w) { masks[n * 4 + w] = m[w]; tot += __popcll(m[w]); }
    cnt[n] = tot;
    out_count[n] = count[n] + (float)tot;
}

// ---------------------------------------------------------------------------
// Kernel 3: flat tile streamer — no ballot, no barrier, no per-block prologue.
// 2512 blocks; block = one 32 KB output tile, 8 f32x4 per thread.
//  tiles [0,2000):   new_cache (class n = tile>>1, half = tile&1)
//  tiles [2000,2512): exch_features
// ---------------------------------------------------------------------------
__global__ __launch_bounds__(256) void k_main(
    const float* __restrict__ features,
    const float* __restrict__ anchor,
    const float* __restrict__ cache,
    const int*   __restrict__ srcrow,
    const unsigned long long* __restrict__ masks,
    const int*   __restrict__ cnt,
    float* __restrict__ out_feat,
    float* __restrict__ out_cache)
{
    const int t    = threadIdx.x;
    const int tile = blockIdx.x;
    if (tile < kATiles) {
        const int n    = tile >> 1;
        const int half = tile & 1;
        const size_t base = (size_t)n * kF4PerClass + (size_t)half * kTileF4;
        const f32x4* src = (const f32x4*)cache + base;
        f32x4*       dst = (f32x4*)out_cache + base;

        const int c = cnt[n];     // broadcast load, in flight with the 8 below
        f32x4 v0 = src[t];
        f32x4 v1 = src[t + 256];
        f32x4 v2 = src[t + 512];
        f32x4 v3 = src[t + 768];
        f32x4 v4 = src[t + 1024];
        f32x4 v5 = src[t + 1280];
        f32x4 v6 = src[t + 1536];
        f32x4 v7 = src[t + 1792];

        if (c) {                  // rare (~2.3% of blocks after dedup by class)
            #pragma unroll
            for (int w = 0; w < 4; ++w) {
                unsigned long long mm = masks[n * 4 + w];
                while (mm) {
                    const int bit = __ffsll((long long)mm) - 1;
                    mm &= mm - 1;
                    const int b = w * 64 + bit;          // ascending b order
                    const f32x4* f = (const f32x4*)features
                                    + (size_t)b * kF4PerClass + (size_t)half * kTileF4;
                    f32x4 f0 = f[t];
                    f32x4 f1 = f[t + 256];
                    f32x4 f2 = f[t + 512];
                    f32x4 f3 = f[t + 768];
                    f32x4 f4 = f[t + 1024];
                    f32x4 f5 = f[t + 1280];
                    f32x4 f6 = f[t + 1536];
                    f32x4 f7 = f[t + 1792];
                    v0 += f0; v1 += f1; v2 += f2; v3 += f3;
                    v4 += f4; v5 += f5; v6 += f6; v7 += f7;
                }
            }
        }
        dst[t]        = v0;
        dst[t + 256]  = v1;
        dst[t + 512]  = v2;
        dst[t + 768]  = v3;
        dst[t + 1024] = v4;
        dst[t + 1280] = v5;
        dst[t + 1536] = v6;
        dst[t + 1792] = v7;
    } else {
        const int bt = tile - kATiles;                   // 0..511
        const int u0 = bt * kTileF4 + t;                 // base f32x4 index
        const f32x4* features4 = (const f32x4*)features;
        const f32x4* anchor4   = (const f32x4*)anchor;
        f32x4*       out4      = (f32x4*)out_feat;

        int s[8];
        #pragma unroll
        for (int i = 0; i < 8; ++i)                      // 8 srcrow loads in flight
            s[i] = srcrow[(u0 + i * 256) >> 7];

        f32x4 v[8];
        #pragma unroll
        for (int i = 0; i < 8; ++i) {                    // 8 data loads in flight
            const int c4 = (u0 + i * 256) & 127;
            const f32x4* sb = (s[i] >= 0) ? features4 : anchor4;
            v[i] = sb[(size_t)(s[i] & 0x7fffffff) * 128 + c4];
        }
        #pragma unroll
        for (int i = 0; i < 8; ++i)
            out4[u0 + i * 256] = v[i];
    }
}

// ---------------------------------------------------------------------------
extern "C" void kernel_launch(void* const* d_in, const int* in_sizes, int n_in,
                              void* d_out, int out_size, void* d_ws, size_t ws_size,
                              hipStream_t stream) {
    const float* features = (const float*)d_in[0];   // (B,A,C)
    const float* labels   = (const float*)d_in[1];   // (B,N)
    const float* anchor   = (const float*)d_in[2];   // (N,A,C)
    const float* cache    = (const float*)d_in[3];   // (N,A,C)
    const float* count    = (const float*)d_in[4];   // (N,)
    const float* rand_u   = (const float*)d_in[5];   // (B,A)

    float* out_feat  = (float*)d_out;                // (B,A,C)
    float* out_cache = out_feat + kFeat;             // (N,A,C)
    float* out_count = out_cache + kCache;           // (N,)

    char* ws = (char*)d_ws;
    unsigned long long* masks = (unsigned long long*)(ws + kWsMasksOff);
    int* cls    = (int*)(ws + kWsClsOff);
    int* srcrow = (int*)(ws + kWsSrcrowOff);
    int* cnt    = (int*)(ws + kWsCntOff);

    k_prep<<<kB / 4, 256, 0, stream>>>(labels, rand_u, cls, srcrow);
    k_plan<<<4, 256, 0, stream>>>(cls, count, masks, cnt, out_count);
    k_main<<<kTiles, 256, 0, stream>>>(features, anchor, cache, srcrow,
                                       masks, cnt, out_feat, out_cache);
}